// Round 7
// baseline (355.905 us; speedup 1.0000x reference)
//
#include <hip/hip_runtime.h>

#define SEQ   1024
#define BATCH 1024
#define TAG   32
#define START 30      // TAG-2
#define ENDT  31      // TAG-1
#define PFD   8       // prefetch ring depth (steps)
#define HALF  512     // steps per wave (fwd wave: 0..511, bwd wave: 1023..512)

__device__ __forceinline__ float rdlane(float v, int j) {
    return __uint_as_float(__builtin_amdgcn_readlane(__float_as_uint(v), j));
}
__device__ __forceinline__ float rdfirst(float v) {
    return __uint_as_float(__builtin_amdgcn_readfirstlane(__float_as_uint(v)));
}

// ---- r1-verified full-width gather core (slow path only) ----
__device__ __forceinline__ void gather_dot_full(float v, const float* __restrict__ coef,
                                                float post, float& vn, float& lg) {
    float r[32];
    #pragma unroll
    for (int j = 0; j < 32; ++j) r[j] = rdlane(v, j);
    __builtin_amdgcn_sched_barrier(0);

    float s0 = r[0] * coef[0];
    float s1 = r[1] * coef[1];
    float s2 = r[2] * coef[2];
    float s3 = r[3] * coef[3];
    float s4 = r[4] * coef[4];
    float s5 = r[5] * coef[5];
    float s6 = r[6] * coef[6];
    float s7 = r[7] * coef[7];
    #pragma unroll
    for (int j = 1; j < 4; ++j) {
        s0 = fmaf(r[8 * j + 0], coef[8 * j + 0], s0);
        s1 = fmaf(r[8 * j + 1], coef[8 * j + 1], s1);
        s2 = fmaf(r[8 * j + 2], coef[8 * j + 2], s2);
        s3 = fmaf(r[8 * j + 3], coef[8 * j + 3], s3);
        s4 = fmaf(r[8 * j + 4], coef[8 * j + 4], s4);
        s5 = fmaf(r[8 * j + 5], coef[8 * j + 5], s5);
        s6 = fmaf(r[8 * j + 6], coef[8 * j + 6], s6);
        s7 = fmaf(r[8 * j + 7], coef[8 * j + 7], s7);
    }
    float dot = ((s0 + s1) + (s2 + s3)) + ((s4 + s5) + (s6 + s7));

    float c  = fmaxf(r[0], 1e-20f);
    float rr = __builtin_amdgcn_rcpf(c);
    lg = __logf(c);
    float sc = post * rr;
    vn = dot * sc;
}

// ---- fast step core: half-split gather via ds_bpermute (LDS permute pipe) ----
// Halves are duplicates (v on lane i == lane i+32). Half h gathers only
// v[16h + j], j = 0..15 (vbase = (lane&32)*6 -> src lane 32h + 16h + j),
// dots against its 16-entry coef slice, then one shfl_xor(32) combines the
// half-partials. Renorm: c = v_0 via readfirstlane (off-chain, parallel to
// dot); log(c) pairs with rcp(c) -- algebraically exact for any c > 0.
__device__ __forceinline__ void step16(float v, const float* __restrict__ eh,
                                       float post, int vbase, float& vn, float& lg) {
    float r[16];
    #pragma unroll
    for (int j = 0; j < 16; ++j)
        r[j] = __uint_as_float((unsigned)__builtin_amdgcn_ds_bpermute(
                   vbase + 4 * j, (int)__float_as_uint(v)));

    float c  = fmaxf(rdfirst(v), 1e-20f);         // v_0 (lane 0), wave-uniform
    float rr = __builtin_amdgcn_rcpf(c);
    lg = __logf(c);
    float sc = post * rr;

    float s0 = r[0] * eh[0];
    float s1 = r[1] * eh[1];
    float s2 = r[2] * eh[2];
    float s3 = r[3] * eh[3];
    float s4 = r[4] * eh[4];
    float s5 = r[5] * eh[5];
    float s6 = r[6] * eh[6];
    float s7 = r[7] * eh[7];
    s0 = fmaf(r[8],  eh[8],  s0);
    s1 = fmaf(r[9],  eh[9],  s1);
    s2 = fmaf(r[10], eh[10], s2);
    s3 = fmaf(r[11], eh[11], s3);
    s4 = fmaf(r[12], eh[12], s4);
    s5 = fmaf(r[13], eh[13], s5);
    s6 = fmaf(r[14], eh[14], s6);
    s7 = fmaf(r[15], eh[15], s7);
    float d = ((s0 + s1) + (s2 + s3)) + ((s4 + s5) + (s6 + s7));
    d += __shfl_xor(d, 32);                       // combine half-partials
    vn = d * sc;
}

// ---------------- slow fallback (r1 verbatim: per-step exact blend) --------
__device__ void slow_path(const float* __restrict__ feats,
                          const float* __restrict__ mask,
                          const float* __restrict__ trans,
                          float* __restrict__ out, int b, int lane) {
    const int i = lane & 31;
    float e[32];
    {
        const float4* tr4 = reinterpret_cast<const float4*>(trans + i * TAG);
        #pragma unroll
        for (int c = 0; c < 8; ++c) {
            float4 t = tr4[c];
            e[4 * c + 0] = __expf(t.x);
            e[4 * c + 1] = __expf(t.y);
            e[4 * c + 2] = __expf(t.z);
            e[4 * c + 3] = __expf(t.w);
        }
    }
    const float* fp = feats + (unsigned)(b * TAG + i);
    const float* mk = mask + (unsigned)b;

    float  v  = (i == START) ? 1.0f : 0.0f;
    double mA = 0.0;

    float fb[PFD], mb[PFD];
    #pragma unroll
    for (int p = 0; p < PFD; ++p) {
        fb[p] = fp[(unsigned)p << 15];
        mb[p] = mk[(unsigned)p << 10];
    }
    for (int t = 0; t < SEQ; t += PFD) {
        #pragma unroll
        for (int p = 0; p < PFD; ++p) {
            unsigned mu = __builtin_amdgcn_readfirstlane(__float_as_uint(mb[p]));
            float fv = fb[p];
            int tn = t + PFD + p; tn = (tn < SEQ) ? tn : (SEQ - 1);
            fb[p] = fp[(unsigned)tn << 15];
            mb[p] = mk[(unsigned)tn << 10];
            if (mu != 0u) {
                float vn, lg;
                gather_dot_full(v, e, __expf(fv), vn, lg);
                if (mu == 0x3f800000u) {
                    v = vn;
                    mA += (double)lg;
                } else {
                    float m   = __uint_as_float(mu);
                    float lv  = __logf(fmaxf(v,  1e-37f));
                    float lvn = __logf(fmaxf(vn, 1e-37f));
                    v = v * __expf(m * (lvn - lv));
                    mA += (double)(m * lg);
                }
            }
        }
    }
    float z = v * __expf(trans[ENDT * TAG + i]);
    float mx = z;
    #pragma unroll
    for (int k = 16; k >= 1; k >>= 1)
        mx = fmaxf(mx, __shfl_xor(mx, k, 32));
    float ss = z * __builtin_amdgcn_rcpf(mx);
    #pragma unroll
    for (int k = 16; k >= 1; k >>= 1)
        ss += __shfl_xor(ss, k, 32);
    if (lane == 0)
        out[b] = (float)(mA + (double)__logf(mx) + (double)__logf(ss));
}

// ---------------- fast path: forward-backward split ------------------------
// logZ = log( e~^T * M1~ * M0~ * e_START ),  e~_i = exp(trans[END][i]).
// Wave 0 (forward):  x <- D_t A x,  t = 0..511       (x0 = e_START)
// Wave 1 (backward): y <- A^T D_t y, t = 1023..512   (y0 = e~)
// Masked steps are identity => uniform-branch skip in both directions.
// Combine: out = mA + mB + log( sum_i x_i y_i ).
__global__ __launch_bounds__(128, 2) void crf_fwd_kernel(
    const float* __restrict__ feats,   // (SEQ, BATCH, TAG)
    const float* __restrict__ mask,    // (SEQ, BATCH)
    const float* __restrict__ trans,   // (TAG, TAG)
    float* __restrict__ out)           // (BATCH,)
{
    const int tid  = threadIdx.x;
    const int lane = tid & 63;
    const int w    = tid >> 6;          // 0 = forward wave, 1 = backward wave
    const int i    = lane & 31;
    const int h    = lane >> 5;         // half: gathers v[16h..16h+15]
    const int b    = blockIdx.x;
    const int vbase = (lane & 32) * 6;  // bpermute byte base: src lane 32h+16h

    __shared__ float  sX[32], sY[32];
    __shared__ double sM[2];
    __shared__ int    sFrac;

    if (tid == 0) sFrac = 0;
    __syncthreads();

    // prepass over own half: binary mask?
    {
        const int tb = w * HALF;
        bool bad = false;
        #pragma unroll
        for (int k = 0; k < 8; ++k) {
            float m = mask[(unsigned)((tb + k * 64 + lane) * BATCH + b)];
            bad |= (m != 0.0f) & (m != 1.0f);
        }
        if (__ballot(bad)) sFrac = 1;
    }
    __syncthreads();

    if (sFrac) {                        // fractional masks: exact blend path
        if (w == 0) slow_path(feats, mask, trans, out, b, lane);
        return;
    }

    const float* fp = feats + (unsigned)(b * TAG + i);
    const float* mk = mask + (unsigned)b;

    if (w == 0) {
        // ---- forward: eh[j] = exp(trans[i][16h + j]) ----
        float eh[16];
        #pragma unroll
        for (int j = 0; j < 16; ++j)
            eh[j] = __expf(trans[i * TAG + 16 * h + j]);

        float  v  = (i == START) ? 1.0f : 0.0f;   // x0 = e_START (guard covers v0=0)
        double mA = 0.0;

        float fb[PFD], mb[PFD];
        #pragma unroll
        for (int p = 0; p < PFD; ++p) {
            fb[p] = fp[(unsigned)p << 15];
            mb[p] = mk[(unsigned)p << 10];
        }
        for (int t = 0; t < HALF; t += PFD) {
            #pragma unroll
            for (int p = 0; p < PFD; ++p) {
                unsigned mu = __builtin_amdgcn_readfirstlane(__float_as_uint(mb[p]));
                float fv = fb[p];
                int tn = t + PFD + p;            // reads ahead into 512..519: harmless
                fb[p] = fp[(unsigned)tn << 15];
                mb[p] = mk[(unsigned)tn << 10];
                if (mu != 0u) {
                    float vn, lg;
                    step16(v, eh, __expf(fv), vbase, vn, lg);
                    v = vn; mA += (double)lg;
                }
            }
        }
        if (lane < 32) sX[i] = v;
        if (lane == 0) sM[0] = mA;
    } else {
        // ---- backward: ehT[j] = exp(trans[16h + j][i]) (column slice) ----
        float ehT[16];
        #pragma unroll
        for (int j = 0; j < 16; ++j)
            ehT[j] = __expf(trans[(16 * h + j) * TAG + i]);

        float  y  = __expf(trans[ENDT * TAG + i]); // y0 = e~
        double mB = 0.0;

        float fb[PFD], mb[PFD];
        #pragma unroll
        for (int p = 0; p < PFD; ++p) {
            fb[p] = fp[(unsigned)(SEQ - 1 - p) << 15];
            mb[p] = mk[(unsigned)(SEQ - 1 - p) << 10];
        }
        for (int s = 0; s < HALF; s += PFD) {
            #pragma unroll
            for (int p = 0; p < PFD; ++p) {
                unsigned mu = __builtin_amdgcn_readfirstlane(__float_as_uint(mb[p]));
                float fv = fb[p];
                int tn = SEQ - 1 - (s + PFD + p); // reads down to 504: harmless
                fb[p] = fp[(unsigned)tn << 15];
                mb[p] = mk[(unsigned)tn << 10];
                if (mu != 0u) {
                    float u = y * __expf(fv);     // D_t scale (off-chain exp)
                    float yn, lg;
                    step16(u, ehT, 1.0f, vbase, yn, lg);
                    y = yn; mB += (double)lg;
                }
            }
        }
        if (lane < 32) sY[i] = y;
        if (lane == 0) sM[1] = mB;
    }
    __syncthreads();

    // ---- combine (wave 0): out = mA + mB + log(sum_i x_i y_i) ----
    if (w == 0) {
        float z = sX[i] * sY[i];                  // all >= 0
        float mx = z;
        #pragma unroll
        for (int k = 16; k >= 1; k >>= 1)
            mx = fmaxf(mx, __shfl_xor(mx, k, 32));
        mx = fmaxf(mx, 1e-30f);
        float ss = z * __builtin_amdgcn_rcpf(mx);
        #pragma unroll
        for (int k = 16; k >= 1; k >>= 1)
            ss += __shfl_xor(ss, k, 32);
        if (lane == 0)
            out[b] = (float)(sM[0] + sM[1]
                             + (double)__logf(mx) + (double)__logf(ss));
    }
}

extern "C" void kernel_launch(void* const* d_in, const int* in_sizes, int n_in,
                              void* d_out, int out_size, void* d_ws, size_t ws_size,
                              hipStream_t stream) {
    const float* feats = (const float*)d_in[0];
    const float* mask  = (const float*)d_in[1];
    const float* trans = (const float*)d_in[2];
    float* out = (float*)d_out;
    crf_fwd_kernel<<<dim3(BATCH), dim3(128), 0, stream>>>(feats, mask, trans, out);
}